// Round 6
// baseline (360.019 us; speedup 1.0000x reference)
//
#include <hip/hip_runtime.h>
#include <hip/hip_bf16.h>

// GroupSupConLoss: loss = mean_i[ lse_i - mean_pos_i ] over anchors with positives.
// sim = E E^T / tau, B=8192, D=1024, tau=0.1.
// R6: 256x256 tile (528 upper-tri blocks, 512 thr, 8 waves 2x4, 128 KiB LDS,
// 2-phase double-buffer). R5 was fetch-bound (245 MB L2-miss traffic ~= whole
// kernel); 256^2 halves logical fetch and doubles MFMA per staged byte.
// Also: zero-init fused into convert kernel, float4 finalize.

#define NROWS 8192
#define DIM   1024
#define TAU_INV 10.0f

#define BM 256
#define BN 256
#define BK 64
#define NTILE (NROWS / BM)                 // 32
#define NBLOCKS (NTILE * (NTILE + 1) / 2)  // 528
#define NKT (DIM / BK)                     // 16
#define TILE_SHORTS (BM * BK)              // 16384 shorts = 32 KiB

typedef __attribute__((ext_vector_type(8))) short short8;
typedef __attribute__((ext_vector_type(4))) float f32x4;

__global__ void convert_bf16_kernel(const float* __restrict__ in,
                                    unsigned short* __restrict__ out,
                                    float* __restrict__ accum_zero, int n4) {
    int gid = blockIdx.x * blockDim.x + threadIdx.x;
    // fused zero-init of the 3*NROWS float accumulators (6144 float4)
    if (gid < 3 * NROWS / 4) {
        float4 z; z.x = 0.f; z.y = 0.f; z.z = 0.f; z.w = 0.f;
        ((float4*)accum_zero)[gid] = z;
    }
    const int stride = gridDim.x * blockDim.x;
    for (int i = gid; i < n4; i += stride) {
        float4 v = ((const float4*)in)[i];
        __hip_bfloat16 b0 = __float2bfloat16(v.x);
        __hip_bfloat16 b1 = __float2bfloat16(v.y);
        __hip_bfloat16 b2 = __float2bfloat16(v.z);
        __hip_bfloat16 b3 = __float2bfloat16(v.w);
        ushort4 o;
        o.x = *(unsigned short*)&b0;
        o.y = *(unsigned short*)&b1;
        o.z = *(unsigned short*)&b2;
        o.w = *(unsigned short*)&b3;
        ((ushort4*)out)[i] = o;
    }
}

__device__ __forceinline__ void gload_lds16(const short* g, short* l) {
    __builtin_amdgcn_global_load_lds(
        (const __attribute__((address_space(1))) unsigned*)g,
        (__attribute__((address_space(3))) unsigned*)l, 16, 0, 0);
}

__launch_bounds__(512)
__global__ void simloss_kernel(const unsigned short* __restrict__ ebf_u,
                               const int* __restrict__ labels,
                               float* __restrict__ exp_sum,
                               float* __restrict__ pos_sum,
                               float* __restrict__ pos_cnt) {
    // [2 buffers][A(32KB) | B(32KB)] = 128 KiB (1 block/CU, 8 waves)
    __shared__ short lds[2 * 2 * TILE_SHORTS];

    const int tid  = threadIdx.x;
    const int lane = tid & 63;
    const int wid  = tid >> 6;   // 0..7
    const int wrow = wid >> 2;   // 0..1  (128-row half)
    const int wcol = wid & 3;    // 0..3  (64-col quarter)

    // XCD-aware bijective swizzle: 528 % 8 == 0, 66 consecutive tiles per XCD.
    const int tile = (blockIdx.x & 7) * (NBLOCKS / 8) + (blockIdx.x >> 3);

    // decode tile -> upper-triangular (ti, tj), ti <= tj
    int u = tile, ti = 0, rowlen = NTILE;
    while (u >= rowlen) { u -= rowlen; ++ti; --rowlen; }
    const int tj = ti + u;
    const int i0 = ti * BM;
    const int j0 = tj * BN;
    const bool offdiag = (ti != tj);

    const short* eg = (const short*)ebf_u;

    f32x4 acc[8][4];
#pragma unroll
    for (int m = 0; m < 8; ++m)
#pragma unroll
        for (int n = 0; n < 4; ++n)
            acc[m][n] = (f32x4)0.0f;

    // staging: 1 KiB chunk = 8 rows x 64 bf16; lane l -> row l>>3, LDS slot l&7.
    // Global column group XOR-swizzled (csrc = (l&7)^(l>>3)) so the swizzled
    // ds_read below is conflict-free while LDS dst stays linear (R4: conflicts->0).
    const int l8 = lane >> 3;
    const int c8 = lane & 7;
    const int csrc = c8 ^ l8;

    // ---- prologue: stage K-tile 0 into buffer 0 ----
    {
        const int kcol = csrc * 8;
#pragma unroll
        for (int c = 0; c < 4; ++c) {
            const int chunk = wid * 4 + c;          // 0..31
            const int row = chunk * 8 + l8;         // 0..255
            gload_lds16(eg + (size_t)(i0 + row) * DIM + kcol, lds + chunk * 512);
            gload_lds16(eg + (size_t)(j0 + row) * DIM + kcol, lds + TILE_SHORTS + chunk * 512);
        }
    }
    __syncthreads();   // drains vmcnt: buffer 0 ready

#pragma unroll 1
    for (int kt = 0; kt < NKT; ++kt) {
        const int cur = kt & 1;
        short* curbuf = lds + cur * 2 * TILE_SHORTS;

        // ---- issue prefetch of K-tile kt+1 into the other buffer ----
        if (kt + 1 < NKT) {
            short* nxtbuf = lds + (cur ^ 1) * 2 * TILE_SHORTS;
            const int kcol = (kt + 1) * BK + csrc * 8;
#pragma unroll
            for (int c = 0; c < 4; ++c) {
                const int chunk = wid * 4 + c;
                const int row = chunk * 8 + l8;
                gload_lds16(eg + (size_t)(i0 + row) * DIM + kcol, nxtbuf + chunk * 512);
                gload_lds16(eg + (size_t)(j0 + row) * DIM + kcol, nxtbuf + TILE_SHORTS + chunk * 512);
            }
        }

        // ---- compute on current buffer ----
#pragma unroll
        for (int ks = 0; ks < 2; ++ks) {
            const int g = ks * 4 + (lane >> 4);     // column group 0..7
            short8 af[8], bf[4];
#pragma unroll
            for (int m = 0; m < 8; ++m) {
                const int r = wrow * 128 + m * 16 + (lane & 15);
                af[m] = *(const short8*)(curbuf + r * BK + ((g ^ (r & 7)) << 3));
            }
#pragma unroll
            for (int n = 0; n < 4; ++n) {
                const int r = wcol * 64 + n * 16 + (lane & 15);
                bf[n] = *(const short8*)(curbuf + TILE_SHORTS + r * BK + ((g ^ (r & 7)) << 3));
            }
#pragma unroll
            for (int m = 0; m < 8; ++m)
#pragma unroll
                for (int n = 0; n < 4; ++n)
                    acc[m][n] = __builtin_amdgcn_mfma_f32_16x16x32_bf16(
                        af[m], bf[n], acc[m][n], 0, 0, 0);
        }

        __syncthreads();   // next buffer ready; current safe to overwrite
    }

    // ---- fused epilogue ----
    // C/D layout: col = lane&15, row = (lane>>4)*4 + reg
    const int rowbase = i0 + wrow * 128;
    const int colbase = j0 + wcol * 64;

    int lc[4];
#pragma unroll
    for (int n = 0; n < 4; ++n)
        lc[n] = labels[colbase + n * 16 + (lane & 15)];

    float ecol[4] = {0, 0, 0, 0};
    float pcol[4] = {0, 0, 0, 0};
    float ccol[4] = {0, 0, 0, 0};

#pragma unroll
    for (int m = 0; m < 8; ++m) {
#pragma unroll
        for (int r = 0; r < 4; ++r) {
            const int row = rowbase + m * 16 + (lane >> 4) * 4 + r;
            const int lr = labels[row];
            float e = 0.0f, p = 0.0f, c = 0.0f;
#pragma unroll
            for (int n = 0; n < 4; ++n) {
                const int col = colbase + n * 16 + (lane & 15);
                const float s = acc[m][n][r] * TAU_INV;
                const bool diag = (row == col);
                const float ex = diag ? 0.0f : __expf(s);
                const bool same = (lr == lc[n]) && !diag;
                const float ps = same ? s : 0.0f;
                const float cs = same ? 1.0f : 0.0f;
                e += ex; p += ps; c += cs;
                ecol[n] += ex; pcol[n] += ps; ccol[n] += cs;
            }
#pragma unroll
            for (int off = 1; off < 16; off <<= 1) {
                e += __shfl_xor(e, off);
                p += __shfl_xor(p, off);
                c += __shfl_xor(c, off);
            }
            if ((lane & 15) == 0) {
                atomicAdd(&exp_sum[row], e);
                atomicAdd(&pos_sum[row], p);
                atomicAdd(&pos_cnt[row], c);
            }
        }
    }

    // col-side (mirror) contributions for off-diagonal tiles: row j gets
    // sum_i exp(s_ij) etc. (s symmetric, label mask symmetric).
    if (offdiag) {
#pragma unroll
        for (int n = 0; n < 4; ++n) {
#pragma unroll
            for (int off = 16; off < 64; off <<= 1) {
                ecol[n] += __shfl_xor(ecol[n], off);
                pcol[n] += __shfl_xor(pcol[n], off);
                ccol[n] += __shfl_xor(ccol[n], off);
            }
            if (lane < 16) {
                const int row = colbase + n * 16 + lane;
                atomicAdd(&exp_sum[row], ecol[n]);
                atomicAdd(&pos_sum[row], pcol[n]);
                atomicAdd(&pos_cnt[row], ccol[n]);
            }
        }
    }
}

__global__ void finalize_kernel(const float* __restrict__ exp_sum,
                                const float* __restrict__ pos_sum,
                                const float* __restrict__ pos_cnt,
                                float* __restrict__ out) {
    __shared__ float s_l[8];
    __shared__ float s_c[8];
    float lsum = 0.0f, csum = 0.0f;
    for (int i4 = threadIdx.x; i4 < NROWS / 4; i4 += blockDim.x) {
        float4 e4 = ((const float4*)exp_sum)[i4];
        float4 p4 = ((const float4*)pos_sum)[i4];
        float4 c4 = ((const float4*)pos_cnt)[i4];
        const float es[4] = {e4.x, e4.y, e4.z, e4.w};
        const float ps[4] = {p4.x, p4.y, p4.z, p4.w};
        const float cs[4] = {c4.x, c4.y, c4.z, c4.w};
#pragma unroll
        for (int k = 0; k < 4; ++k) {
            const bool has = cs[k] > 0.5f;
            const float li = logf(es[k]) - ps[k] / fmaxf(cs[k], 1.0f);
            lsum += has ? li : 0.0f;
            csum += has ? 1.0f : 0.0f;
        }
    }
#pragma unroll
    for (int off = 1; off < 64; off <<= 1) {
        lsum += __shfl_xor(lsum, off);
        csum += __shfl_xor(csum, off);
    }
    const int w = threadIdx.x >> 6;
    if ((threadIdx.x & 63) == 0) { s_l[w] = lsum; s_c[w] = csum; }
    __syncthreads();
    if (threadIdx.x == 0) {
        float L = 0.0f, C = 0.0f;
        for (int i = 0; i < (int)(blockDim.x >> 6); ++i) { L += s_l[i]; C += s_c[i]; }
        out[0] = L / fmaxf(C, 1.0f);
    }
}

extern "C" void kernel_launch(void* const* d_in, const int* in_sizes, int n_in,
                              void* d_out, int out_size, void* d_ws, size_t ws_size,
                              hipStream_t stream) {
    const float* emb   = (const float*)d_in[0];
    const int* labels  = (const int*)d_in[1];
    float* out         = (float*)d_out;

    char* ws = (char*)d_ws;
    unsigned short* ebf = (unsigned short*)ws;                       // 16 MiB
    float* exp_sum = (float*)(ws + (size_t)NROWS * DIM * 2);         // 3*32 KiB
    float* pos_sum = exp_sum + NROWS;
    float* pos_cnt = exp_sum + 2 * NROWS;

    convert_bf16_kernel<<<1024, 256, 0, stream>>>(emb, ebf, exp_sum, NROWS * DIM / 4);
    simloss_kernel<<<NBLOCKS, 512, 0, stream>>>(ebf, labels, exp_sum, pos_sum, pos_cnt);
    finalize_kernel<<<1, 512, 0, stream>>>(exp_sum, pos_sum, pos_cnt, out);
}

// Round 7
// 281.177 us; speedup vs baseline: 1.2804x; 1.2804x over previous
//
#include <hip/hip_runtime.h>
#include <hip/hip_bf16.h>

// GroupSupConLoss: loss = mean_i[ lse_i - mean_pos_i ] over anchors with positives.
// sim = E E^T / tau, B=8192, D=1024, tau=0.1.
// R7: back to 128x128 tiles (2080 upper-tri blocks, 2 blocks/CU) but with a
// 3-deep software pipeline: BK=32, 4 LDS buffers (64 KiB), raw s_barrier +
// counted s_waitcnt vmcnt(8) per K-step (never drain to 0 in steady state).
// R5/R6 were latency-bound: the __syncthreads full-drain exposed load latency
// every K-iter (MfmaUtil 9-13%). Liveness: group t stages tile t+3 into
// buf[(t+3)&3]=buf[(t-1)&3], last read in group t-1, protected by group t's
// top barrier. vmcnt(8) leaves tiles t+1,t+2 (4 loads each) in flight.

#define NROWS 8192
#define DIM   1024
#define TAU_INV 10.0f

#define BM 128
#define BN 128
#define BK 32
#define NTILE (NROWS / BM)                 // 64
#define NBLOCKS (NTILE * (NTILE + 1) / 2)  // 2080
#define NKT (DIM / BK)                     // 32
#define ABUF_SHORTS (BM * BK)              // 4096 shorts = 8 KiB
#define BUF_SHORTS (2 * ABUF_SHORTS)       // A+B = 16 KiB

typedef __attribute__((ext_vector_type(8))) short short8;
typedef __attribute__((ext_vector_type(4))) float f32x4;

__global__ void convert_bf16_kernel(const float* __restrict__ in,
                                    unsigned short* __restrict__ out,
                                    float* __restrict__ accum_zero, int n4) {
    int gid = blockIdx.x * blockDim.x + threadIdx.x;
    if (gid < 3 * NROWS / 4) {
        float4 z; z.x = 0.f; z.y = 0.f; z.z = 0.f; z.w = 0.f;
        ((float4*)accum_zero)[gid] = z;
    }
    const int stride = gridDim.x * blockDim.x;
    for (int i = gid; i < n4; i += stride) {
        float4 v = ((const float4*)in)[i];
        __hip_bfloat16 b0 = __float2bfloat16(v.x);
        __hip_bfloat16 b1 = __float2bfloat16(v.y);
        __hip_bfloat16 b2 = __float2bfloat16(v.z);
        __hip_bfloat16 b3 = __float2bfloat16(v.w);
        ushort4 o;
        o.x = *(unsigned short*)&b0;
        o.y = *(unsigned short*)&b1;
        o.z = *(unsigned short*)&b2;
        o.w = *(unsigned short*)&b3;
        ((ushort4*)out)[i] = o;
    }
}

__device__ __forceinline__ void gload_lds16(const short* g, short* l) {
    __builtin_amdgcn_global_load_lds(
        (const __attribute__((address_space(1))) unsigned*)g,
        (__attribute__((address_space(3))) unsigned*)l, 16, 0, 0);
}

__launch_bounds__(256)
__global__ void simloss_kernel(const unsigned short* __restrict__ ebf_u,
                               const int* __restrict__ labels,
                               float* __restrict__ exp_sum,
                               float* __restrict__ pos_sum,
                               float* __restrict__ pos_cnt) {
    // 4 buffers x (A 8KiB + B 8KiB) = 64 KiB -> 2 blocks/CU
    __shared__ short lds[4 * BUF_SHORTS];

    const int tid  = threadIdx.x;
    const int lane = tid & 63;
    const int wid  = tid >> 6;   // 0..3
    const int wrow = wid >> 1;   // 0..1
    const int wcol = wid & 1;    // 0..1

    // XCD-aware bijective swizzle: 2080 % 8 == 0.
    const int tile = (blockIdx.x & 7) * (NBLOCKS / 8) + (blockIdx.x >> 3);

    // decode tile -> upper-triangular (ti, tj), ti <= tj
    int u = tile, ti = 0, rowlen = NTILE;
    while (u >= rowlen) { u -= rowlen; ++ti; --rowlen; }
    const int tj = ti + u;
    const int i0 = ti * BM;
    const int j0 = tj * BN;
    const bool offdiag = (ti != tj);

    const short* eg = (const short*)ebf_u;

    f32x4 acc[4][4];
#pragma unroll
    for (int m = 0; m < 4; ++m)
#pragma unroll
        for (int n = 0; n < 4; ++n)
            acc[m][n] = (f32x4)0.0f;

    // Staging: 1 KiB chunk = 16 rows x 32 bf16. lane l -> row l>>2 in chunk,
    // LDS 16B slot l&3. Read swizzle: slot = g ^ ((row>>1)&3)  (optimal: each
    // bank-quad hit exactly 8x = b128's inherent 8 phases, 0 extra conflict).
    // Staging pre-swizzles the GLOBAL column-group so LDS dst stays linear.
    const int lrow = lane >> 2;                       // 0..15 row in chunk
    const int csrc = (lane & 3) ^ ((lane >> 3) & 3);  // swizzled global col-group

#define STAGE(t, b)                                                          \
    {                                                                        \
        short* Ab = lds + (b) * BUF_SHORTS;                                  \
        short* Bb = Ab + ABUF_SHORTS;                                        \
        const int kc = (t) * BK + csrc * 8;                                  \
        _Pragma("unroll")                                                    \
        for (int c = 0; c < 2; ++c) {                                        \
            const int ch = wid * 2 + c;            /* chunk 0..7 */          \
            const int gr = ch * 16 + lrow;         /* row 0..127 */          \
            gload_lds16(eg + (size_t)(i0 + gr) * DIM + kc, Ab + ch * 512);   \
            gload_lds16(eg + (size_t)(j0 + gr) * DIM + kc, Bb + ch * 512);   \
        }                                                                    \
    }

    // ---- prologue: stage tiles 0,1,2 (12 loads in flight per wave) ----
    STAGE(0, 0)
    STAGE(1, 1)
    STAGE(2, 2)

    const int g = lane >> 4;          // K col-group 0..3 (8 elems each)

#pragma unroll 1
    for (int t = 0; t < NKT; ++t) {
        // wait: tile t's 4 loads are the oldest; leave t+1,t+2 in flight.
        if (t < NKT - 2)       asm volatile("s_waitcnt vmcnt(8)" ::: "memory");
        else if (t == NKT - 2) asm volatile("s_waitcnt vmcnt(4)" ::: "memory");
        else                   asm volatile("s_waitcnt vmcnt(0)" ::: "memory");
        __builtin_amdgcn_s_barrier();   // all waves: tile t in LDS; group t-1 compute done

        if (t + 3 < NKT) STAGE(t + 3, (t + 3) & 3)

        const short* Ab = lds + (t & 3) * BUF_SHORTS;
        const short* Bb = Ab + ABUF_SHORTS;

        short8 af[4], bf[4];
#pragma unroll
        for (int m = 0; m < 4; ++m) {
            const int r = wrow * 64 + m * 16 + (lane & 15);
            af[m] = *(const short8*)(Ab + r * BK + ((g ^ ((r >> 1) & 3)) << 3));
        }
#pragma unroll
        for (int n = 0; n < 4; ++n) {
            const int r = wcol * 64 + n * 16 + (lane & 15);
            bf[n] = *(const short8*)(Bb + r * BK + ((g ^ ((r >> 1) & 3)) << 3));
        }
        __builtin_amdgcn_s_setprio(1);
#pragma unroll
        for (int m = 0; m < 4; ++m)
#pragma unroll
            for (int n = 0; n < 4; ++n)
                acc[m][n] = __builtin_amdgcn_mfma_f32_16x16x32_bf16(
                    af[m], bf[n], acc[m][n], 0, 0, 0);
        __builtin_amdgcn_s_setprio(0);
    }
#undef STAGE

    // ---- fused epilogue (proven R5) ----
    // C/D layout: col = lane&15, row = (lane>>4)*4 + reg
    const int rowbase = i0 + wrow * 64;
    const int colbase = j0 + wcol * 64;

    int lc[4];
#pragma unroll
    for (int n = 0; n < 4; ++n)
        lc[n] = labels[colbase + n * 16 + (lane & 15)];

    float ecol[4] = {0, 0, 0, 0};
    float pcol[4] = {0, 0, 0, 0};
    float ccol[4] = {0, 0, 0, 0};

#pragma unroll
    for (int m = 0; m < 4; ++m) {
#pragma unroll
        for (int r = 0; r < 4; ++r) {
            const int row = rowbase + m * 16 + (lane >> 4) * 4 + r;
            const int lr = labels[row];
            float e = 0.0f, p = 0.0f, c = 0.0f;
#pragma unroll
            for (int n = 0; n < 4; ++n) {
                const int col = colbase + n * 16 + (lane & 15);
                const float s = acc[m][n][r] * TAU_INV;
                const bool diag = (row == col);
                const float ex = diag ? 0.0f : __expf(s);
                const bool same = (lr == lc[n]) && !diag;
                const float ps = same ? s : 0.0f;
                const float cs = same ? 1.0f : 0.0f;
                e += ex; p += ps; c += cs;
                ecol[n] += ex; pcol[n] += ps; ccol[n] += cs;
            }
#pragma unroll
            for (int off = 1; off < 16; off <<= 1) {
                e += __shfl_xor(e, off);
                p += __shfl_xor(p, off);
                c += __shfl_xor(c, off);
            }
            if ((lane & 15) == 0) {
                atomicAdd(&exp_sum[row], e);
                atomicAdd(&pos_sum[row], p);
                atomicAdd(&pos_cnt[row], c);
            }
        }
    }

    // col-side (mirror) contributions for off-diagonal tiles.
    if (offdiag) {
#pragma unroll
        for (int n = 0; n < 4; ++n) {
#pragma unroll
            for (int off = 16; off < 64; off <<= 1) {
                ecol[n] += __shfl_xor(ecol[n], off);
                pcol[n] += __shfl_xor(pcol[n], off);
                ccol[n] += __shfl_xor(ccol[n], off);
            }
            if (lane < 16) {
                const int row = colbase + n * 16 + lane;
                atomicAdd(&exp_sum[row], ecol[n]);
                atomicAdd(&pos_sum[row], pcol[n]);
                atomicAdd(&pos_cnt[row], ccol[n]);
            }
        }
    }
}

__global__ void finalize_kernel(const float* __restrict__ exp_sum,
                                const float* __restrict__ pos_sum,
                                const float* __restrict__ pos_cnt,
                                float* __restrict__ out) {
    __shared__ float s_l[8];
    __shared__ float s_c[8];
    float lsum = 0.0f, csum = 0.0f;
    for (int i4 = threadIdx.x; i4 < NROWS / 4; i4 += blockDim.x) {
        float4 e4 = ((const float4*)exp_sum)[i4];
        float4 p4 = ((const float4*)pos_sum)[i4];
        float4 c4 = ((const float4*)pos_cnt)[i4];
        const float es[4] = {e4.x, e4.y, e4.z, e4.w};
        const float ps[4] = {p4.x, p4.y, p4.z, p4.w};
        const float cs[4] = {c4.x, c4.y, c4.z, c4.w};
#pragma unroll
        for (int k = 0; k < 4; ++k) {
            const bool has = cs[k] > 0.5f;
            const float li = logf(es[k]) - ps[k] / fmaxf(cs[k], 1.0f);
            lsum += has ? li : 0.0f;
            csum += has ? 1.0f : 0.0f;
        }
    }
#pragma unroll
    for (int off = 1; off < 64; off <<= 1) {
        lsum += __shfl_xor(lsum, off);
        csum += __shfl_xor(csum, off);
    }
    const int w = threadIdx.x >> 6;
    if ((threadIdx.x & 63) == 0) { s_l[w] = lsum; s_c[w] = csum; }
    __syncthreads();
    if (threadIdx.x == 0) {
        float L = 0.0f, C = 0.0f;
        for (int i = 0; i < (int)(blockDim.x >> 6); ++i) { L += s_l[i]; C += s_c[i]; }
        out[0] = L / fmaxf(C, 1.0f);
    }
}

extern "C" void kernel_launch(void* const* d_in, const int* in_sizes, int n_in,
                              void* d_out, int out_size, void* d_ws, size_t ws_size,
                              hipStream_t stream) {
    const float* emb   = (const float*)d_in[0];
    const int* labels  = (const int*)d_in[1];
    float* out         = (float*)d_out;

    char* ws = (char*)d_ws;
    unsigned short* ebf = (unsigned short*)ws;                       // 16 MiB
    float* exp_sum = (float*)(ws + (size_t)NROWS * DIM * 2);         // 3*32 KiB
    float* pos_sum = exp_sum + NROWS;
    float* pos_cnt = exp_sum + 2 * NROWS;

    convert_bf16_kernel<<<1024, 256, 0, stream>>>(emb, ebf, exp_sum, NROWS * DIM / 4);
    simloss_kernel<<<NBLOCKS, 256, 0, stream>>>(ebf, labels, exp_sum, pos_sum, pos_cnt);
    finalize_kernel<<<1, 256, 0, stream>>>(exp_sum, pos_sum, pos_cnt, out);
}